// Round 11
// baseline (178.534 us; speedup 1.0000x reference)
//
#include <hip/hip_runtime.h>
#include <math.h>

#define F_OUT     32
#define GRID_DIM  32
#define NUM_VOX   (GRID_DIM * GRID_DIM * GRID_DIM)

#define NPB   64             // nodes per bucket; bucket = dst >> 6
#define NBKT  1024           // bucket table size (Nn <= 65536)
#define SEB   4096           // edges per sort block (mean frag = 4 edges = 64B line)
#define SCS   132            // sC row stride (floats): 528 B, 16B-aligned
#define DEGS  125            // degree slot within sC row
#define ECAP  3072           // owner work-list capacity (mean 1024, +~40 sigma)

// ---------- monotonic float<->uint encoding for atomicMax on signed floats ----
__device__ __forceinline__ unsigned int enc_f32(float f) {
    unsigned int u = __float_as_uint(f);
    return (u & 0x80000000u) ? ~u : (u | 0x80000000u);
}
__device__ __forceinline__ float dec_f32(unsigned int e) {
    return (e & 0x80000000u) ? __uint_as_float(e ^ 0x80000000u)
                             : __uint_as_float(~e);
}

// ---------- K1: block-local counting sort, MLP-8 pass A ----------------------
__global__ __launch_bounds__(512) void sort_kernel(
    const int*   __restrict__ src,
    const int*   __restrict__ dst,
    const float* __restrict__ x,
    const float* __restrict__ pseudo,
    float4* __restrict__ payload,          // [nSB * SEB]
    unsigned int* __restrict__ off_tab,    // [nSB][NBKT] packed: local_start | cnt<<16
    int E)
{
    __shared__ unsigned int sHist[NBKT];   // hist -> cursor (4 KB)
    __shared__ unsigned int sStart[NBKT];  // exclusive starts (4 KB)
    __shared__ unsigned int sWTot[8];      // per-wave scan totals
    __shared__ __align__(16) float4 sPay[SEB];   // staged payload (64 KB)

    const int t    = threadIdx.x;
    const int lane = t & 63;
    const int wv   = t >> 6;
    const int e0   = blockIdx.x * SEB;
    const bool full = (e0 + SEB <= E);

    for (int i = t; i < NBKT; i += 512) sHist[i] = 0;
    __syncthreads();

    // pass A: batched loads -> 8 independent x-gathers in flight -> histogram.
    // validity = index range (e < E); dst==65535 is a legal id, no sentinel.
    unsigned short dloc[8];
    float4 pay[8];
    if (full) {                            // branchless fast path (exact fit)
        int   dd[8], ss[8];
        float pp0[8], pp1[8], pp2[8], xj[8];
        #pragma unroll
        for (int i = 0; i < 8; ++i) {
            int e = e0 + i * 512 + t;
            dd[i] = dst[e]; ss[i] = src[e];
            pp0[i] = pseudo[3 * e]; pp1[i] = pseudo[3 * e + 1]; pp2[i] = pseudo[3 * e + 2];
        }
        #pragma unroll
        for (int i = 0; i < 8; ++i) xj[i] = x[ss[i]];    // 8 gathers, all in flight
        #pragma unroll
        for (int i = 0; i < 8; ++i) {
            unsigned int q2 = (unsigned int)(pp2[i] * 65535.0f + 0.5f) & 0xFFFFu;
            unsigned int w  = q2 | ((unsigned int)(dd[i] & 63) << 16);
            dloc[i] = (unsigned short)dd[i];
            pay[i]  = make_float4(pp0[i], pp1[i], xj[i], __uint_as_float(w));
            atomicAdd(&sHist[dd[i] >> 6], 1u);
        }
    } else {
        #pragma unroll
        for (int i = 0; i < 8; ++i) {
            int e = e0 + i * 512 + t;
            if (e < E) {
                int d = dst[e];
                float p0 = pseudo[3 * e], p1 = pseudo[3 * e + 1], p2 = pseudo[3 * e + 2];
                float xjv = x[src[e]];
                unsigned int q2 = (unsigned int)(p2 * 65535.0f + 0.5f) & 0xFFFFu;
                unsigned int w  = q2 | ((unsigned int)(d & 63) << 16);
                dloc[i] = (unsigned short)d;
                pay[i]  = make_float4(p0, p1, xjv, __uint_as_float(w));
                atomicAdd(&sHist[d >> 6], 1u);
            } else dloc[i] = 0;
        }
    }
    __syncthreads();

    // exclusive scan of 1024 buckets: pair-sum + wave shfl-scan + cross-wave
    unsigned int a0 = sHist[2 * t], a1 = sHist[2 * t + 1];
    unsigned int pairSum = a0 + a1;
    unsigned int incl = pairSum;
    #pragma unroll
    for (int d = 1; d < 64; d <<= 1) {
        unsigned int v = __shfl_up(incl, d, 64);
        if (lane >= d) incl += v;
    }
    if (lane == 63) sWTot[wv] = incl;
    __syncthreads();
    unsigned int wofs = 0, total = 0;
    #pragma unroll
    for (int w = 0; w < 8; ++w) {
        unsigned int v = sWTot[w];
        if (w < wv) wofs += v;
        total += v;
    }
    unsigned int ex = wofs + incl - pairSum;
    sStart[2 * t]     = ex;
    sStart[2 * t + 1] = ex + a0;
    sHist[2 * t]      = ex;            // cursor copy
    sHist[2 * t + 1]  = ex + a0;
    __syncthreads();

    // pass B: place payloads into LDS by bucket (same validity rule)
    #pragma unroll
    for (int i = 0; i < 8; ++i) {
        int e = e0 + i * 512 + t;
        if (e < E) {
            unsigned int slot = atomicAdd(&sHist[dloc[i] >> 6], 1u);
            sPay[slot] = pay[i];
        }
    }
    __syncthreads();

    // streamout: coalesced 16B stores to this block's private slab
    for (unsigned int i = t; i < total; i += 512)
        payload[(size_t)e0 + i] = sPay[i];

    // packed offset table, coalesced row write
    for (int b = t; b < NBKT; b += 512) {
        unsigned int s = sStart[b];
        unsigned int nxt = (b < NBKT - 1) ? sStart[b + 1] : total;
        off_tab[(size_t)blockIdx.x * NBKT + b] = s | ((nxt - s) << 16);
    }
}

// ---------- K1b: transpose off_tab [nSB][NBKT] -> [NBKT][nSB] ----------------
__global__ __launch_bounds__(256) void transpose_kernel(
    const unsigned int* __restrict__ in, unsigned int* __restrict__ outT,
    int rows, int cols)
{
    __shared__ unsigned int tile[32][33];
    const int tx = threadIdx.x & 31, ty = threadIdx.x >> 5;   // 32x8
    const int c0 = blockIdx.x * 32, r0 = blockIdx.y * 32;
    #pragma unroll
    for (int r = ty; r < 32; r += 8) {
        int row = r0 + r, col = c0 + tx;
        tile[r][tx] = (row < rows && col < cols) ? in[(size_t)row * cols + col] : 0u;
    }
    __syncthreads();
    #pragma unroll
    for (int r = ty; r < 32; r += 8) {
        int col = c0 + r;      // out row
        int row = r0 + tx;     // out col
        if (col < cols && row < rows) outT[(size_t)col * rows + row] = tile[tx][r];
    }
}

// ---------- per-edge accumulation: 9 scattered LDS atomics -------------------
__device__ __forceinline__ void process_edge(float4 r, float* sC)
{
    float xj = r.z;
    unsigned int w = __float_as_uint(r.w);
    int   rel = (int)((w >> 16) & 63u);
    float p2  = (float)(w & 0xFFFFu) * (1.0f / 65535.0f);

    float v0 = r.x * 4.0f, v1 = r.y * 4.0f, v2 = p2 * 4.0f;
    float i0 = fminf(fmaxf(floorf(v0), 0.0f), 3.0f);
    float i1 = fminf(fmaxf(floorf(v1), 0.0f), 3.0f);
    float i2 = fminf(fmaxf(floorf(v2), 0.0f), 3.0f);
    float f0 = v0 - i0, f1 = v1 - i1, f2 = v2 - i2;
    float g0 = 1.0f - f0, g1 = 1.0f - f1, g2 = 1.0f - f2;
    int k = (int)i0 + 5 * (int)i1 + 25 * (int)i2;        // 0..93

    float w00 = g0 * g1, w10 = f0 * g1, w01 = g0 * f1, w11 = f0 * f1;
    float a2 = xj * g2, b2 = xj * f2;
    float* row = sC + rel * SCS;
    atomicAdd(row + k +  0, w00 * a2);
    atomicAdd(row + k +  1, w10 * a2);
    atomicAdd(row + k +  5, w01 * a2);
    atomicAdd(row + k +  6, w11 * a2);
    atomicAdd(row + k + 25, w00 * b2);
    atomicAdd(row + k + 26, w10 * b2);
    atomicAdd(row + k + 30, w01 * b2);
    atomicAdd(row + k + 31, w11 * b2);
    atomicAdd(row + DEGS, 1.0f);                         // degree
}

// ---------- K2: owner block — edge accumulate + GEMM + h write ---------------
__global__ __launch_bounds__(512) void owner_kernel(
    const float4* __restrict__ payload,
    const unsigned int* __restrict__ off_tabT,  // [NBKT][nSB] packed (transposed)
    const float* __restrict__ W,        // [125,32]
    const float* __restrict__ x,        // [N,1]
    const float* __restrict__ W_root,   // [32]
    const float* __restrict__ bias,     // [32]
    float4* __restrict__ h4,            // [N*8] = h[N,32] as float4
    int Nn, int nSB)
{
    __shared__ __align__(16) float sC[NPB * SCS];   // 33792 B
    __shared__ unsigned int sEdge[ECAP];            // 12288 B
    __shared__ unsigned int sNe;

    const int t = threadIdx.x;
    const int b = blockIdx.x;
    const int lane = t & 63;

    // zero sC
    for (int i = t; i < NPB * SCS / 4; i += 512)
        *(float4*)&sC[i * 4] = make_float4(0.f, 0.f, 0.f, 0.f);
    if (t == 0) sNe = 0;

    // my fragment — COALESCED row read of the transposed table
    unsigned int cnt = 0, start_g = 0;
    if (t < nSB) {
        unsigned int packed = off_tabT[(size_t)b * nSB + t];
        start_g = (unsigned int)t * SEB + (packed & 0xFFFFu);
        cnt = packed >> 16;
    }
    __syncthreads();

    // wave-level exclusive prefix of cnt -> compact work list offsets
    unsigned int incl = cnt;
    #pragma unroll
    for (int d = 1; d < 64; d <<= 1) {
        unsigned int v = __shfl_up(incl, d, 64);
        if (lane >= d) incl += v;
    }
    unsigned int wtot = __shfl(incl, 63, 64);
    unsigned int wbase = 0;
    if (lane == 63 && wtot > 0) wbase = atomicAdd(&sNe, wtot);
    wbase = __shfl(wbase, 63, 64);
    unsigned int off = wbase + incl - cnt;

    for (unsigned int j = 0; j < cnt; ++j) {
        unsigned int p = off + j;
        if (p < ECAP) sEdge[p] = start_g + j;
        else process_edge(payload[start_g + j], sC);   // statistically unreachable
    }
    __syncthreads();

    // edge phase: 2 payloads in flight per thread
    int ne = (int)sNe; if (ne > ECAP) ne = ECAP;
    for (int i = t; i < ne; i += 1024) {
        float4 r0 = payload[sEdge[i]];
        int j = i + 512;
        bool hj = (j < ne);
        float4 r1 = r0;
        if (hj) r1 = payload[sEdge[j]];
        process_edge(r0, sC);
        if (hj) process_edge(r1, sC);
    }
    __syncthreads();

    // dense GEMM: [64 x 125] @ [125 x 32], 4 channels/thread (rolled, no spill)
    const int node = t & 63;
    const int cg   = t >> 6;                 // wave-uniform channel group 0..7
    const float* crow = sC + node * SCS;
    float4 acc = make_float4(0.f, 0.f, 0.f, 0.f);
    #pragma unroll 8
    for (int k4 = 0; k4 < 31; ++k4) {        // k = 0..123
        float4 r = *(const float4*)&crow[k4 * 4];
        const float* wp = W + (k4 * 4) * F_OUT + cg * 4;
        float4 w0 = *(const float4*)(wp);
        float4 w1 = *(const float4*)(wp + F_OUT);
        float4 w2 = *(const float4*)(wp + 2 * F_OUT);
        float4 w3 = *(const float4*)(wp + 3 * F_OUT);
        acc.x += r.x * w0.x + r.y * w1.x + r.z * w2.x + r.w * w3.x;
        acc.y += r.x * w0.y + r.y * w1.y + r.z * w2.y + r.w * w3.y;
        acc.z += r.x * w0.z + r.y * w1.z + r.z * w2.z + r.w * w3.z;
        acc.w += r.x * w0.w + r.y * w1.w + r.z * w2.w + r.w * w3.w;
    }
    {   // k = 124
        float r = crow[124];
        const float* wp = W + 124 * F_OUT + cg * 4;
        acc.x += r * wp[0]; acc.y += r * wp[1];
        acc.z += r * wp[2]; acc.w += r * wp[3];
    }
    float dg = fmaxf(crow[DEGS], 1.0f);
    int   n  = b * NPB + node;
    float xn = (n < Nn) ? x[n] : 0.0f;
    float4 wr = *(const float4*)(W_root + cg * 4);
    float4 bs = *(const float4*)(bias + cg * 4);
    __syncthreads();                          // all sC reads done

    // epilogue into sC slots 0..31 per node
    if (n < Nn) {
        float h;
        h = acc.x / dg + xn * wr.x + bs.x; h = h > 0.f ? h : expm1f(h); sC[node * SCS + cg * 4 + 0] = h;
        h = acc.y / dg + xn * wr.y + bs.y; h = h > 0.f ? h : expm1f(h); sC[node * SCS + cg * 4 + 1] = h;
        h = acc.z / dg + xn * wr.z + bs.z; h = h > 0.f ? h : expm1f(h); sC[node * SCS + cg * 4 + 2] = h;
        h = acc.w / dg + xn * wr.w + bs.w; h = h > 0.f ? h : expm1f(h); sC[node * SCS + cg * 4 + 3] = h;
    }
    __syncthreads();

    // coalesced h write
    const int n0 = b * NPB;
    for (int item = t; item < NPB * 8; item += 512) {
        int nr = item >> 3, q = item & 7;
        if (n0 + nr >= Nn) break;
        h4[(size_t)n0 * 8 + item] = *(const float4*)&sC[nr * SCS + q * 4];
    }
}

// ---------- K3: voxel scatter-max --------------------------------------------
__global__ __launch_bounds__(256) void voxmax_kernel(
    const float* __restrict__ h,        // [N,32]
    const float* __restrict__ pos,      // [N,3]
    unsigned int* __restrict__ pooled,  // [NUM_VOX,32] encoded
    int Nn)
{
    int gid = blockIdx.x * 256 + threadIdx.x;
    int n = gid >> 5, o = gid & 31;
    if (n >= Nn) return;
    float hv = h[(size_t)n * F_OUT + o];
    int vx = min(max((int)floorf(pos[3 * n + 0] * (float)GRID_DIM), 0), GRID_DIM - 1);
    int vy = min(max((int)floorf(pos[3 * n + 1] * (float)GRID_DIM), 0), GRID_DIM - 1);
    int vz = min(max((int)floorf(pos[3 * n + 2] * (float)GRID_DIM), 0), GRID_DIM - 1);
    int vidx = vx + GRID_DIM * vy + GRID_DIM * GRID_DIM * vz;
    atomicMax(&pooled[(size_t)vidx * F_OUT + o], enc_f32(hv));
}

// ---------- K4: decode, empty voxels -> 0 ------------------------------------
__global__ __launch_bounds__(256) void finalize_kernel(
    const unsigned int* __restrict__ pooled,
    float* __restrict__ out, int M)
{
    int i = blockIdx.x * blockDim.x + threadIdx.x;
    if (i >= M) return;
    unsigned int u = pooled[i];
    out[i] = (u == 0u) ? 0.0f : dec_f32(u);
}

// ============================ launcher =======================================
extern "C" void kernel_launch(void* const* d_in, const int* in_sizes, int n_in,
                              void* d_out, int out_size, void* d_ws, size_t ws_size,
                              hipStream_t stream) {
    const float* x       = (const float*)d_in[0];
    const int*   ei      = (const int*)  d_in[1];
    const float* pseudo  = (const float*)d_in[2];
    const float* pos     = (const float*)d_in[3];
    const float* W       = (const float*)d_in[4];
    const float* W_root  = (const float*)d_in[5];
    const float* bias    = (const float*)d_in[6];
    float* out = (float*)d_out;

    const int E   = in_sizes[1] / 2;
    const int Nn  = in_sizes[0];                  // F_IN == 1, Nn <= 65536
    const int nSB = (E + SEB - 1) / SEB;          // sort blocks (256 here)
    const int nb  = (Nn + NPB - 1) / NPB;         // owner buckets (1024 here)

    // workspace: [pooled 4MB][off_tab 1MB][off_tabT 1MB][payload 16.8MB][h 8MB]
    const size_t pooled_b = (size_t)NUM_VOX * F_OUT * 4;
    const size_t off_b    = ((size_t)nSB * NBKT * 4 + 255) & ~(size_t)255;
    const size_t pay_b    = (size_t)nSB * SEB * 16;
    unsigned int* pooled   = (unsigned int*)d_ws;
    unsigned int* off_tab  = (unsigned int*)((char*)d_ws + pooled_b);
    unsigned int* off_tabT = (unsigned int*)((char*)d_ws + pooled_b + off_b);
    float4*       payload  = (float4*)((char*)d_ws + pooled_b + 2 * off_b);
    float4*       h4       = (float4*)((char*)d_ws + pooled_b + 2 * off_b + pay_b);

    hipMemsetAsync(pooled, 0, pooled_b, stream);

    sort_kernel<<<nSB, 512, 0, stream>>>(ei, ei + E, x, pseudo, payload, off_tab, E);
    transpose_kernel<<<dim3((NBKT + 31) / 32, (nSB + 31) / 32), 256, 0, stream>>>(
        off_tab, off_tabT, nSB, NBKT);
    owner_kernel<<<nb, 512, 0, stream>>>(payload, off_tabT, W, x, W_root, bias,
                                         h4, Nn, nSB);
    voxmax_kernel<<<(Nn * F_OUT + 255) / 256, 256, 0, stream>>>(
        (const float*)h4, pos, pooled, Nn);

    const int M = (out_size < NUM_VOX * F_OUT) ? out_size : NUM_VOX * F_OUT;
    finalize_kernel<<<(M + 255) / 256, 256, 0, stream>>>(pooled, out, M);
}